// Round 12
// baseline (184.249 us; speedup 1.0000x reference)
//
#include <hip/hip_runtime.h>

typedef unsigned short u16;
typedef unsigned int u32;
typedef __attribute__((ext_vector_type(2))) unsigned int u32x2;
typedef __attribute__((ext_vector_type(8))) short bf16x8;
typedef __attribute__((ext_vector_type(4))) float f32x4;
typedef __attribute__((ext_vector_type(16))) float f32x16;

#define TOK   4096   // B*T
#define EMB   1024
#define NQKV  3072
#define TSEQ  2048
#define NH    16

__device__ __forceinline__ u16 f2b(float f) {
  union { float f; unsigned u; } v; v.f = f;
  unsigned r = v.u + 0x7FFFu + ((v.u >> 16) & 1u);
  return (u16)(r >> 16);
}

// half-up scalar bf16 (bit-identical to pack_rn's per-half rounding)
__device__ __forceinline__ u16 f2b_hu(float f) {
  return (u16)((__float_as_uint(f) + 0x8000u) >> 16);
}

// pack bf16(a) low16, bf16(b) high16 (round half-up)
__device__ __forceinline__ u32 pack_rn(float a, float b) {
  u32 ua = __float_as_uint(a) + 0x8000u;
  u32 ub = __float_as_uint(b) + 0x8000u;
  return __builtin_amdgcn_perm(ub, ua, 0x07060302u);
}

__device__ __forceinline__ f32x16 zero16() {
  f32x16 z;
#pragma unroll
  for (int i = 0; i < 16; i++) z[i] = 0.f;
  return z;
}

// async global->LDS, 16B per lane; LDS dest is wave-uniform base + lane*16
__device__ __forceinline__ void gload16(const void* g, void* l) {
  __builtin_amdgcn_global_load_lds((const __attribute__((address_space(1))) void*)g,
                                   (__attribute__((address_space(3))) void*)l, 16, 0, 0);
}

// ---------------- fused prep: x->bf16, w_qkv^T, w_out^T ----------------

__global__ __launch_bounds__(256) void prep_kernel(const float* __restrict__ x,
                                                   u16* __restrict__ x_bf,
                                                   const float* __restrict__ w_qkv,
                                                   u16* __restrict__ wqkvT,
                                                   const float* __restrict__ w_out,
                                                   u16* __restrict__ woutT) {
  __shared__ u16 sm[64][65];
  int bid = blockIdx.x, tid = threadIdx.x;
  if (bid < 4096) {                       // cvt: 1M float4 elements
    int i = bid * 256 + tid;
    float4 v = ((const float4*)x)[i];
    union { u16 us[4]; uint2 u2; } o;
    o.us[0] = f2b(v.x); o.us[1] = f2b(v.y); o.us[2] = f2b(v.z); o.us[3] = f2b(v.w);
    ((uint2*)x_bf)[i] = o.u2;
    return;
  }
  const float* src; u16* dst; int R, C, bx, by;
  if (bid < 4096 + 768) {                 // w_qkv: [1024][3072] -> [3072][1024]
    int t = bid - 4096; bx = t % 48; by = t / 48;
    src = w_qkv; dst = wqkvT; R = EMB; C = NQKV;
  } else {                                // w_out: [1024][1024] -> [1024][1024]
    int t = bid - 4096 - 768; bx = t & 15; by = t >> 4;
    src = w_out; dst = woutT; R = EMB; C = EMB;
  }
  int c0 = bx * 64, r0 = by * 64;
#pragma unroll
  for (int i = 0; i < 16; i++) {
    int idx = tid + i * 256;
    int r = idx >> 6, c = idx & 63;
    sm[r][c] = f2b(src[(size_t)(r0 + r) * C + c0 + c]);
  }
  __syncthreads();
  // vectorized writeback: thread -> (cc, 16 consecutive rr) = 2x uint4 stores
  int cc2 = tid >> 2, rr0 = (tid & 3) * 16;
  union { u16 us[16]; uint4 v4[2]; } o;
#pragma unroll
  for (int j = 0; j < 16; j++) o.us[j] = sm[rr0 + j][cc2];
  *(uint4*)&dst[(size_t)(c0 + cc2) * R + r0 + rr0]     = o.v4[0];
  *(uint4*)&dst[(size_t)(c0 + cc2) * R + r0 + rr0 + 8] = o.v4[1];
}

// ---------------- GEMM: C[m][n] = sum_k A[m][k]*Bt[n][k] + bias[n] ----------------
// R5/R8-PROVEN FORM: global_load_lds width-16 + BOTH-SIDES XOR swizzle (rule #21),
// double-buffered 2-phase loop, one __syncthreads per 64-wide K-step, 256 threads.
// T1 XCD-chunked remap (CW>0): xcd=bid&7 owns a CW x CH tile rectangle -> per-XCD
// ~5MB L2-resident working set; MEASURED on gemm0 (R10/R11): FETCH 40->33.9MB,
// dur 48.4->46.3us. CW=0: plain 2D grid (R8-proven for gemm1).
// MODE 0: Q/K uint2 bf16 [bh][t][d]; V TRANSPOSED [bh][d][t]. MODE 1: float4 fp32.

template <int MODE, int TN, int CW, int CH>
__global__ __launch_bounds__(256) void gemm_bt(const u16* __restrict__ A,
                                               const u16* __restrict__ Bt,
                                               const float* __restrict__ bias,
                                               u16* __restrict__ qb, u16* __restrict__ kb,
                                               u16* __restrict__ vb, float* __restrict__ outp,
                                               int K, int N) {
  constexpr int CT = TN / 32;            // B col-tiles per wave
  constexpr int RB = TN / 32;            // B staging rounds per wave (8 rows each)
  __shared__ u16 As[2][128][64];
  __shared__ u16 Bs[2][TN][64];
  int tid = threadIdx.x;
  int bx, by;
  if constexpr (CW > 0) {                // T1 chunked remap (bijective)
    int bid = blockIdx.x;
    int xcd = bid & 7, idx = bid >> 3;
    bx = (xcd & 1) * CW + idx % CW;
    by = (xcd >> 1) * CH + idx / CW;
  } else {
    bx = blockIdx.x; by = blockIdx.y;
  }
  int m0 = by * 128, n0 = bx * TN;
  int lane = tid & 63, wid = tid >> 6;
  int wm = (wid >> 1) * 64;
  int wn = (wid & 1) * (TN / 2);
  int l15 = lane & 15, quad = lane >> 4;
  // staging: lane covers row (lane>>3) of its 8-row group; SOURCE column is the
  // inverse-swizzled 16B group so the linear LDS write lands swizzled (m173).
  int srow = lane >> 3;
  int scol = (((lane & 7) ^ srow) * 8);

  f32x4 acc[4][CT];
#pragma unroll
  for (int i = 0; i < 4; i++)
#pragma unroll
    for (int j = 0; j < CT; j++) acc[i][j] = (f32x4){0.f, 0.f, 0.f, 0.f};

  const u16* Ag = A + (size_t)(m0 + wid * 32 + srow) * K + scol;
  const u16* Bg = Bt + (size_t)(n0 + wid * (TN / 4) + srow) * K + scol;

  // prologue: stage tile 0 into buf 0
#pragma unroll
  for (int i = 0; i < 4; i++)
    gload16(Ag + (size_t)(i * 8) * K, &As[0][wid * 32 + i * 8][0]);
#pragma unroll
  for (int i = 0; i < RB; i++)
    gload16(Bg + (size_t)(i * 8) * K, &Bs[0][wid * (TN / 4) + i * 8][0]);
  __syncthreads();

  int cur = 0;
  for (int k0 = 0; k0 < K; k0 += 64) {
    if (k0 + 64 < K) {                   // issue next-tile loads; fly under MFMA
      int kn = k0 + 64;
#pragma unroll
      for (int i = 0; i < 4; i++)
        gload16(Ag + (size_t)(i * 8) * K + kn, &As[cur ^ 1][wid * 32 + i * 8][0]);
#pragma unroll
      for (int i = 0; i < RB; i++)
        gload16(Bg + (size_t)(i * 8) * K + kn, &Bs[cur ^ 1][wid * (TN / 4) + i * 8][0]);
    }

#pragma unroll
    for (int ks = 0; ks < 2; ks++) {
      bf16x8 af[4], bfr[CT];
#pragma unroll
      for (int rt = 0; rt < 4; rt++)
        af[rt] = *(const bf16x8*)&As[cur][wm + rt * 16 + l15][((ks * 4 + quad) ^ (l15 & 7)) * 8];
#pragma unroll
      for (int ct = 0; ct < CT; ct++)
        bfr[ct] = *(const bf16x8*)&Bs[cur][wn + ct * 16 + l15][((ks * 4 + quad) ^ (l15 & 7)) * 8];
#pragma unroll
      for (int rt = 0; rt < 4; rt++)
#pragma unroll
        for (int ct = 0; ct < CT; ct++)
          acc[rt][ct] = __builtin_amdgcn_mfma_f32_16x16x32_bf16(bfr[ct], af[rt], acc[rt][ct], 0, 0, 0);
    }
    __syncthreads();                     // vmcnt(0)+lgkmcnt(0)+barrier: next tile
    cur ^= 1;                            // landed, all readers of cur done
  }

#pragma unroll
  for (int rt = 0; rt < 4; rt++) {
#pragma unroll
    for (int ct = 0; ct < CT; ct++) {
      int m = m0 + wm + rt * 16 + l15;
      int nb = n0 + wn + ct * 16 + quad * 4;
      float4 b4 = *(const float4*)&bias[nb];
      float v0 = acc[rt][ct][0] + b4.x, v1 = acc[rt][ct][1] + b4.y;
      float v2 = acc[rt][ct][2] + b4.z, v3 = acc[rt][ct][3] + b4.w;
      if (MODE == 0) {
        int sel = nb >> 10;              // block-uniform (128-col blocks)
        int c = nb & 1023;
        int h = c >> 6, d0 = c & 63;
        int b = m >> 11, t = m & 2047;
        if (sel == 2) {
          // V transposed: Vt[bh][d][t]
          size_t vbase = ((((size_t)b * NH + h) * 64 + d0) * TSEQ) + t;
          vb[vbase]            = f2b_hu(v0);
          vb[vbase + TSEQ]     = f2b_hu(v1);
          vb[vbase + 2 * TSEQ] = f2b_hu(v2);
          vb[vbase + 3 * TSEQ] = f2b_hu(v3);
        } else {
          u16* dst = sel ? kb : qb;
          union { u32 u[2]; uint2 u2; } o;
          o.u[0] = pack_rn(v0, v1);
          o.u[1] = pack_rn(v2, v3);
          *(uint2*)&dst[((((size_t)b * NH + h) * TSEQ + t) << 6) + d0] = o.u2;
        }
      } else {
        float4 o = {v0, v1, v2, v3};
        *(float4*)&outp[(size_t)m * N + nb] = o;
      }
    }
  }
}

// ---------------- flash attention: 32x32 MFMA, 4 waves = 2 q-subtiles x 2 key-halves --
// R8 structure + NEW: DOUBLE-BUFFERED K/V LDS -- one __syncthreads per K-tile
// (was 2). Parity proof: step kt computes buf[kt&1]; tile kt+1 is written into
// buf[(kt+1)&1], whose readers ran at step kt-1 (before this step's barrier), and
// buf[kt&1]'s writes ran at step kt-1 (also before it) -- one barrier covers both.
// Occupancy is preserved by OVERLAYING the post-loop combine buffers (Cmb/Lmb)
// on the K/V space via a union (they are live on disjoint sides of the final
// barrier): union = 34.8KB -> still 4 blocks/CU, 16 waves/CU.
// XCD-chunked bh (T1); associative fixed-M softmax, par wave-split over keys;
// T12 cvt_pk+permlane P transform; T5 setprio around MFMA clusters (m191).
// l_i accumulated into 4 independent partials (breaks 32-deep dependent chain).

__global__ __launch_bounds__(256, 4) void attn_kernel(const u16* __restrict__ Qb,
                                                      const u16* __restrict__ Kb,
                                                      const u16* __restrict__ Vtb,
                                                      u16* __restrict__ O) {
  __shared__ union __align__(16) SM {
    struct { u16 Ks[2][64][68]; u16 Vt[2][64][68]; } kv;      // 34,816 B
    struct { float Cmb[2][16][64][2]; float Lmb[2][32]; } cb; // 16,640 B
  } sm;

  const float SCL = 0.18033688f;   // (1/8) * log2(e)
  const float MOFF = 16.0f;

  int phys = blockIdx.x;
  int xcd = phys & 7;
  int cuL = (phys >> 3) & 31;
  int slot = phys >> 8;                 // 0..3
  int bh = xcd * 4 + slot;
  int qt = (slot & 1) ? (31 - cuL) : cuL;

  int tid = threadIdx.x, lane = tid & 63, w = tid >> 6;
  int sub = w & 1, par = w >> 1;
  int l31 = lane & 31, h = lane >> 5;
  const size_t hoff = (size_t)bh * TSEQ * 64;

  int qw = qt * 64 + sub * 32;      // wave's q base
  int qg = qw + l31;                // lane's q column

  // Q B-operand fragments: qf[s] = Q[qg][s*16 + h*8 .. +7]
  bf16x8 qf[4];
  {
    const u16* qp = Qb + hoff + (size_t)qg * 64 + h * 8;
#pragma unroll
    for (int s = 0; s < 4; s++) qf[s] = *(const bf16x8*)(qp + s * 16);
  }

  f32x16 acc[2];
  acc[0] = zero16(); acc[1] = zero16();
  float lp0 = 0.f, lp1 = 0.f, lp2 = 0.f, lp3 = 0.f;   // 4-way l partials

  // staging: thread covers K row r cols [cb,cb+16) and V^T row r cols [cb,cb+16)
  int r = tid >> 2, cb = (tid & 3) * 16;
  bf16x8 kr0, kr1, vr0, vr1;

  // prologue: tile 0 -> regs -> buf0; tile 1 -> regs (in flight)
  {
    const u16* kg = Kb + hoff + (size_t)r * 64 + cb;
    const u16* vg = Vtb + hoff + (size_t)r * TSEQ + cb;
    kr0 = *(const bf16x8*)kg;       kr1 = *(const bf16x8*)(kg + 8);
    vr0 = *(const bf16x8*)vg;       vr1 = *(const bf16x8*)(vg + 8);
    *(bf16x8*)&sm.kv.Ks[0][r][cb]     = kr0;
    *(bf16x8*)&sm.kv.Ks[0][r][cb + 8] = kr1;
    *(bf16x8*)&sm.kv.Vt[0][r][cb]     = vr0;
    *(bf16x8*)&sm.kv.Vt[0][r][cb + 8] = vr1;
    if (qt >= 1) {
      const u16* kg1 = Kb + hoff + (size_t)(64 + r) * 64 + cb;
      const u16* vg1 = Vtb + hoff + (size_t)r * TSEQ + 64 + cb;
      kr0 = *(const bf16x8*)kg1;    kr1 = *(const bf16x8*)(kg1 + 8);
      vr0 = *(const bf16x8*)vg1;    vr1 = *(const bf16x8*)(vg1 + 8);
    }
  }

  for (int kt = 0; kt <= qt; kt++) {
    __syncthreads();                       // buf[cur] visible AND buf[cur^1] readers done
    int cur = kt & 1;
    if (kt + 1 <= qt) {                    // write in-flight tile kt+1 into buf^1
      *(bf16x8*)&sm.kv.Ks[cur ^ 1][r][cb]     = kr0;
      *(bf16x8*)&sm.kv.Ks[cur ^ 1][r][cb + 8] = kr1;
      *(bf16x8*)&sm.kv.Vt[cur ^ 1][r][cb]     = vr0;
      *(bf16x8*)&sm.kv.Vt[cur ^ 1][r][cb + 8] = vr1;
    }
    if (kt + 2 <= qt) {                    // issue reg-loads of tile kt+2
      const u16* kg = Kb + hoff + (size_t)((kt + 2) * 64 + r) * 64 + cb;
      const u16* vg = Vtb + hoff + (size_t)r * TSEQ + (kt + 2) * 64 + cb;
      kr0 = *(const bf16x8*)kg;     kr1 = *(const bf16x8*)(kg + 8);
      vr0 = *(const bf16x8*)vg;     vr1 = *(const bf16x8*)(vg + 8);
    }

    int kbt = kt * 64 + par * 32;          // wave's 32-key chunk base
    if (kbt <= qw + 31) {                  // skip fully-masked quadrant (wave-uniform)
      // S^T quadrant = K Q^T : col = q (l31), rows = 32 keys of this chunk
      f32x16 sacc = zero16();
      __builtin_amdgcn_s_setprio(1);
#pragma unroll
      for (int s = 0; s < 4; s++) {
        bf16x8 kf = *(const bf16x8*)&sm.kv.Ks[cur][par * 32 + l31][s * 16 + h * 8];
        sacc = __builtin_amdgcn_mfma_f32_32x32x16_bf16(kf, qf[s], sacc, 0, 0, 0);
      }
      __builtin_amdgcn_s_setprio(0);

      if (kbt + 31 > qw) {                 // diagonal band: apply causal mask
#pragma unroll
        for (int rr = 0; rr < 16; rr++) {
          int key = kbt + (rr & 3) + 8 * (rr >> 2) + 4 * h;
          if (key > qg) sacc[rr] = -1e30f;
        }
      }

#pragma unroll
      for (int rr = 0; rr < 16; rr++) {
        float p = exp2f(__builtin_fmaf(sacc[rr], SCL, -MOFF));
        sacc[rr] = p;
        if ((rr & 3) == 0)      lp0 += p;
        else if ((rr & 3) == 1) lp1 += p;
        else if ((rr & 3) == 2) lp2 += p;
        else                    lp3 += p;
      }

      // per 16-key chunk: C->B transform = 4 cvt_pk + 2 permlane32_swap (T12)
#pragma unroll
      for (int s2 = 0; s2 < 2; s2++) {
        u32 u0, u1, u2, u3;
        asm("v_cvt_pk_bf16_f32 %0, %1, %2" : "=v"(u0) : "v"(sacc[8 * s2 + 0]), "v"(sacc[8 * s2 + 1]));
        asm("v_cvt_pk_bf16_f32 %0, %1, %2" : "=v"(u1) : "v"(sacc[8 * s2 + 2]), "v"(sacc[8 * s2 + 3]));
        asm("v_cvt_pk_bf16_f32 %0, %1, %2" : "=v"(u2) : "v"(sacc[8 * s2 + 4]), "v"(sacc[8 * s2 + 5]));
        asm("v_cvt_pk_bf16_f32 %0, %1, %2" : "=v"(u3) : "v"(sacc[8 * s2 + 6]), "v"(sacc[8 * s2 + 7]));
        u32x2 r02 = __builtin_amdgcn_permlane32_swap(u0, u2, false, false);
        u32x2 r13 = __builtin_amdgcn_permlane32_swap(u1, u3, false, false);
        union { u32 d[4]; bf16x8 v; } pf;
        pf.d[0] = r02[0];
        pf.d[1] = r13[0];
        pf.d[2] = r02[1];
        pf.d[3] = r13[1];
        __builtin_amdgcn_s_setprio(1);
#pragma unroll
        for (int dt = 0; dt < 2; dt++) {
          bf16x8 vf = *(const bf16x8*)&sm.kv.Vt[cur][dt * 32 + l31][par * 32 + s2 * 16 + h * 8];
          acc[dt] = __builtin_amdgcn_mfma_f32_32x32x16_bf16(vf, pf.v, acc[dt], 0, 0, 0);
        }
        __builtin_amdgcn_s_setprio(0);
      }
    }
  }

  float l_i = (lp0 + lp1) + (lp2 + lp3);
  l_i += __shfl_xor(l_i, 32);              // combine h halves within wave

  __syncthreads();                          // K/V reads done -> overlay Cmb/Lmb
  if (par == 1) {                           // export partials
#pragma unroll
    for (int dt = 0; dt < 2; dt++)
#pragma unroll
      for (int pr = 0; pr < 8; pr++) {
        sm.cb.Cmb[sub][dt * 8 + pr][lane][0] = acc[dt][2 * pr];
        sm.cb.Cmb[sub][dt * 8 + pr][lane][1] = acc[dt][2 * pr + 1];
      }
    if (h == 0) sm.cb.Lmb[sub][l31] = l_i;
  }
  __syncthreads();
  if (par == 0) {                           // combine + write O
#pragma unroll
    for (int dt = 0; dt < 2; dt++)
#pragma unroll
      for (int pr = 0; pr < 8; pr++) {
        acc[dt][2 * pr]     += sm.cb.Cmb[sub][dt * 8 + pr][lane][0];
        acc[dt][2 * pr + 1] += sm.cb.Cmb[sub][dt * 8 + pr][lane][1];
      }
    float lt = l_i + sm.cb.Lmb[sub][l31];
    float inv = 1.0f / lt;

    int b = bh >> 4, head = bh & 15;
    size_t rowbase = ((size_t)b * TSEQ + qg) * 1024 + head * 64;
#pragma unroll
    for (int dt = 0; dt < 2; dt++)
#pragma unroll
      for (int G = 0; G < 4; G++) {
        union { u32 u[2]; uint2 u2; } o;
        o.u[0] = pack_rn(acc[dt][4 * G + 0] * inv, acc[dt][4 * G + 1] * inv);
        o.u[1] = pack_rn(acc[dt][4 * G + 2] * inv, acc[dt][4 * G + 3] * inv);
        *(uint2*)&O[rowbase + dt * 32 + G * 8 + 4 * h] = o.u2;
      }
  }
}

// ---------------- launch ----------------

extern "C" void kernel_launch(void* const* d_in, const int* in_sizes, int n_in,
                              void* d_out, int out_size, void* d_ws, size_t ws_size,
                              hipStream_t stream) {
  (void)in_sizes; (void)n_in; (void)out_size; (void)ws_size;
  const float* x     = (const float*)d_in[0];
  const float* w_qkv = (const float*)d_in[1];
  const float* b_qkv = (const float*)d_in[2];
  const float* w_out = (const float*)d_in[3];
  const float* b_out = (const float*)d_in[4];
  float* out = (float*)d_out;

  char* p = (char*)d_ws;
  u16* x_bf  = (u16*)p; p += (size_t)TOK * EMB * 2;       // 8 MiB
  u16* wqkvT = (u16*)p; p += (size_t)NQKV * EMB * 2;      // 6 MiB
  u16* woutT = (u16*)p; p += (size_t)EMB * EMB * 2;       // 2 MiB
  u16* Qb    = (u16*)p; p += (size_t)32 * TSEQ * 64 * 2;  // 8 MiB  [bh][t][d]
  u16* Kb    = (u16*)p; p += (size_t)32 * TSEQ * 64 * 2;  //        [bh][t][d]
  u16* Vtb   = (u16*)p; p += (size_t)32 * TSEQ * 64 * 2;  //        [bh][d][t] (direct from gemm0)
  u16* attn_o = (u16*)p;                                  // 8 MiB

  prep_kernel<<<dim3(4096 + 768 + 256), 256, 0, stream>>>(x, x_bf, w_qkv, wqkvT, w_out, woutT);
  // gemm0: grid 768 = 8 XCDs x (12 cols x 8 rows); per-XCD set ~5 MB (R10-proven)
  gemm_bt<0, 128, 12, 8><<<dim3(768), 256, 0, stream>>>(x_bf, wqkvT, b_qkv,
                                                        Qb, Kb, Vtb, nullptr, EMB, NQKV);
  attn_kernel<<<dim3(1024), 256, 0, stream>>>(Qb, Kb, Vtb, attn_o);
  // gemm1: R8-proven plain 2D grid
  gemm_bt<1, 64, 0, 0><<<dim3(EMB / 64, TOK / 128), 256, 0, stream>>>(attn_o, woutT, b_out,
                                                                      nullptr, nullptr, nullptr, out, EMB, EMB);
}

// Round 13
// 182.170 us; speedup vs baseline: 1.0114x; 1.0114x over previous
//
#include <hip/hip_runtime.h>

typedef unsigned short u16;
typedef unsigned int u32;
typedef __attribute__((ext_vector_type(2))) unsigned int u32x2;
typedef __attribute__((ext_vector_type(8))) short bf16x8;
typedef __attribute__((ext_vector_type(4))) float f32x4;
typedef __attribute__((ext_vector_type(16))) float f32x16;

#define TOK   4096   // B*T
#define EMB   1024
#define NQKV  3072
#define TSEQ  2048
#define NH    16

__device__ __forceinline__ u16 f2b(float f) {
  union { float f; unsigned u; } v; v.f = f;
  unsigned r = v.u + 0x7FFFu + ((v.u >> 16) & 1u);
  return (u16)(r >> 16);
}

// half-up scalar bf16 (bit-identical to pack_rn's per-half rounding)
__device__ __forceinline__ u16 f2b_hu(float f) {
  return (u16)((__float_as_uint(f) + 0x8000u) >> 16);
}

// pack bf16(a) low16, bf16(b) high16 (round half-up)
__device__ __forceinline__ u32 pack_rn(float a, float b) {
  u32 ua = __float_as_uint(a) + 0x8000u;
  u32 ub = __float_as_uint(b) + 0x8000u;
  return __builtin_amdgcn_perm(ub, ua, 0x07060302u);
}

__device__ __forceinline__ f32x16 zero16() {
  f32x16 z;
#pragma unroll
  for (int i = 0; i < 16; i++) z[i] = 0.f;
  return z;
}

// async global->LDS, 16B per lane; LDS dest is wave-uniform base + lane*16
__device__ __forceinline__ void gload16(const void* g, void* l) {
  __builtin_amdgcn_global_load_lds((const __attribute__((address_space(1))) void*)g,
                                   (__attribute__((address_space(3))) void*)l, 16, 0, 0);
}

// ---------------- fused prep: x->bf16, w_qkv^T, w_out^T ----------------

__global__ __launch_bounds__(256) void prep_kernel(const float* __restrict__ x,
                                                   u16* __restrict__ x_bf,
                                                   const float* __restrict__ w_qkv,
                                                   u16* __restrict__ wqkvT,
                                                   const float* __restrict__ w_out,
                                                   u16* __restrict__ woutT) {
  __shared__ u16 sm[64][65];
  int bid = blockIdx.x, tid = threadIdx.x;
  if (bid < 4096) {                       // cvt: 1M float4 elements
    int i = bid * 256 + tid;
    float4 v = ((const float4*)x)[i];
    union { u16 us[4]; uint2 u2; } o;
    o.us[0] = f2b(v.x); o.us[1] = f2b(v.y); o.us[2] = f2b(v.z); o.us[3] = f2b(v.w);
    ((uint2*)x_bf)[i] = o.u2;
    return;
  }
  const float* src; u16* dst; int R, C, bx, by;
  if (bid < 4096 + 768) {                 // w_qkv: [1024][3072] -> [3072][1024]
    int t = bid - 4096; bx = t % 48; by = t / 48;
    src = w_qkv; dst = wqkvT; R = EMB; C = NQKV;
  } else {                                // w_out: [1024][1024] -> [1024][1024]
    int t = bid - 4096 - 768; bx = t & 15; by = t >> 4;
    src = w_out; dst = woutT; R = EMB; C = EMB;
  }
  int c0 = bx * 64, r0 = by * 64;
#pragma unroll
  for (int i = 0; i < 16; i++) {
    int idx = tid + i * 256;
    int r = idx >> 6, c = idx & 63;
    sm[r][c] = f2b(src[(size_t)(r0 + r) * C + c0 + c]);
  }
  __syncthreads();
  // vectorized writeback: thread -> (cc, 16 consecutive rr) = 2x uint4 stores
  int cc2 = tid >> 2, rr0 = (tid & 3) * 16;
  union { u16 us[16]; uint4 v4[2]; } o;
#pragma unroll
  for (int j = 0; j < 16; j++) o.us[j] = sm[rr0 + j][cc2];
  *(uint4*)&dst[(size_t)(c0 + cc2) * R + r0 + rr0]     = o.v4[0];
  *(uint4*)&dst[(size_t)(c0 + cc2) * R + r0 + rr0 + 8] = o.v4[1];
}

// ---------------- GEMM: C[m][n] = sum_k A[m][k]*Bt[n][k] + bias[n] ----------------
// SESSION-BEST FORM (counter-proven): global_load_lds width-16 + BOTH-SIDES XOR
// swizzle (rule #21; conflicts 9.4M->0), double-buffered 2-phase loop, one
// __syncthreads per 64-wide K-step, 256 threads.
// T1 XCD-chunked remap (CW>0): xcd=bid&7 owns a CW x CH tile rectangle -> per-XCD
// ~5MB L2-resident working set; MEASURED (R10-R12, 15 replays): FETCH 40->33.9MB,
// dispatch 48.4->46.3us. CW=0: plain 2D grid (gemm1; remap null there).
// Structural alternatives all regressed (R6 ring, R9 256x192, R12 attn-dbuf):
// below ~3 blocks/CU exposed latency beats reuse; 8-phase gains non-graftable.
// MODE 0: Q/K uint2 bf16 [bh][t][d]; V TRANSPOSED [bh][d][t]. MODE 1: float4 fp32.

template <int MODE, int TN, int CW, int CH>
__global__ __launch_bounds__(256) void gemm_bt(const u16* __restrict__ A,
                                               const u16* __restrict__ Bt,
                                               const float* __restrict__ bias,
                                               u16* __restrict__ qb, u16* __restrict__ kb,
                                               u16* __restrict__ vb, float* __restrict__ outp,
                                               int K, int N) {
  constexpr int CT = TN / 32;            // B col-tiles per wave
  constexpr int RB = TN / 32;            // B staging rounds per wave (8 rows each)
  __shared__ u16 As[2][128][64];
  __shared__ u16 Bs[2][TN][64];
  int tid = threadIdx.x;
  int bx, by;
  if constexpr (CW > 0) {                // T1 chunked remap (bijective)
    int bid = blockIdx.x;
    int xcd = bid & 7, idx = bid >> 3;
    bx = (xcd & 1) * CW + idx % CW;
    by = (xcd >> 1) * CH + idx / CW;
  } else {
    bx = blockIdx.x; by = blockIdx.y;
  }
  int m0 = by * 128, n0 = bx * TN;
  int lane = tid & 63, wid = tid >> 6;
  int wm = (wid >> 1) * 64;
  int wn = (wid & 1) * (TN / 2);
  int l15 = lane & 15, quad = lane >> 4;
  // staging: lane covers row (lane>>3) of its 8-row group; SOURCE column is the
  // inverse-swizzled 16B group so the linear LDS write lands swizzled (m173).
  int srow = lane >> 3;
  int scol = (((lane & 7) ^ srow) * 8);

  f32x4 acc[4][CT];
#pragma unroll
  for (int i = 0; i < 4; i++)
#pragma unroll
    for (int j = 0; j < CT; j++) acc[i][j] = (f32x4){0.f, 0.f, 0.f, 0.f};

  const u16* Ag = A + (size_t)(m0 + wid * 32 + srow) * K + scol;
  const u16* Bg = Bt + (size_t)(n0 + wid * (TN / 4) + srow) * K + scol;

  // prologue: stage tile 0 into buf 0
#pragma unroll
  for (int i = 0; i < 4; i++)
    gload16(Ag + (size_t)(i * 8) * K, &As[0][wid * 32 + i * 8][0]);
#pragma unroll
  for (int i = 0; i < RB; i++)
    gload16(Bg + (size_t)(i * 8) * K, &Bs[0][wid * (TN / 4) + i * 8][0]);
  __syncthreads();

  int cur = 0;
  for (int k0 = 0; k0 < K; k0 += 64) {
    if (k0 + 64 < K) {                   // issue next-tile loads; fly under MFMA
      int kn = k0 + 64;
#pragma unroll
      for (int i = 0; i < 4; i++)
        gload16(Ag + (size_t)(i * 8) * K + kn, &As[cur ^ 1][wid * 32 + i * 8][0]);
#pragma unroll
      for (int i = 0; i < RB; i++)
        gload16(Bg + (size_t)(i * 8) * K + kn, &Bs[cur ^ 1][wid * (TN / 4) + i * 8][0]);
    }

#pragma unroll
    for (int ks = 0; ks < 2; ks++) {
      bf16x8 af[4], bfr[CT];
#pragma unroll
      for (int rt = 0; rt < 4; rt++)
        af[rt] = *(const bf16x8*)&As[cur][wm + rt * 16 + l15][((ks * 4 + quad) ^ (l15 & 7)) * 8];
#pragma unroll
      for (int ct = 0; ct < CT; ct++)
        bfr[ct] = *(const bf16x8*)&Bs[cur][wn + ct * 16 + l15][((ks * 4 + quad) ^ (l15 & 7)) * 8];
#pragma unroll
      for (int rt = 0; rt < 4; rt++)
#pragma unroll
        for (int ct = 0; ct < CT; ct++)
          acc[rt][ct] = __builtin_amdgcn_mfma_f32_16x16x32_bf16(bfr[ct], af[rt], acc[rt][ct], 0, 0, 0);
    }
    __syncthreads();                     // vmcnt(0)+lgkmcnt(0)+barrier: next tile
    cur ^= 1;                            // landed, all readers of cur done
  }

#pragma unroll
  for (int rt = 0; rt < 4; rt++) {
#pragma unroll
    for (int ct = 0; ct < CT; ct++) {
      int m = m0 + wm + rt * 16 + l15;
      int nb = n0 + wn + ct * 16 + quad * 4;
      float4 b4 = *(const float4*)&bias[nb];
      float v0 = acc[rt][ct][0] + b4.x, v1 = acc[rt][ct][1] + b4.y;
      float v2 = acc[rt][ct][2] + b4.z, v3 = acc[rt][ct][3] + b4.w;
      if (MODE == 0) {
        int sel = nb >> 10;              // block-uniform (128-col blocks)
        int c = nb & 1023;
        int h = c >> 6, d0 = c & 63;
        int b = m >> 11, t = m & 2047;
        if (sel == 2) {
          // V transposed: Vt[bh][d][t]
          size_t vbase = ((((size_t)b * NH + h) * 64 + d0) * TSEQ) + t;
          vb[vbase]            = f2b_hu(v0);
          vb[vbase + TSEQ]     = f2b_hu(v1);
          vb[vbase + 2 * TSEQ] = f2b_hu(v2);
          vb[vbase + 3 * TSEQ] = f2b_hu(v3);
        } else {
          u16* dst = sel ? kb : qb;
          union { u32 u[2]; uint2 u2; } o;
          o.u[0] = pack_rn(v0, v1);
          o.u[1] = pack_rn(v2, v3);
          *(uint2*)&dst[((((size_t)b * NH + h) * TSEQ + t) << 6) + d0] = o.u2;
        }
      } else {
        float4 o = {v0, v1, v2, v3};
        *(float4*)&outp[(size_t)m * N + nb] = o;
      }
    }
  }
}

// ---------------- flash attention: 32x32 MFMA, 4 waves = 2 q-subtiles x 2 key-halves --
// SESSION-BEST STRUCTURE (R8, part of the 181.4 best total): grid 1024, 4
// blocks/CU, 16 waves/CU. XCD-chunked bh (T1): 4 heads/XCD, K/V L2-resident;
// qt = (slot&1) ? 31-cuL : cuL (per-CU slot pairs sum to 62). Associative
// fixed-M softmax, par wave-split over keys, partial (O,l) combined via LDS.
// T12 cvt_pk+permlane P transform; T5 setprio around MFMA clusters (m191).
// (R7 128-row, R12 dbuf variants both failed/nulled: with 4 independent
// blocks/CU, TLP already fills barrier waits -- single-buffer is optimal here.)

__global__ __launch_bounds__(256, 4) void attn_kernel(const u16* __restrict__ Qb,
                                                      const u16* __restrict__ Kb,
                                                      const u16* __restrict__ Vtb,
                                                      u16* __restrict__ O) {
  __shared__ u16 Ks[64][68];
  __shared__ u16 Vt[64][68];
  __shared__ float Cmb[2][16][64][2];   // [sub][pair][lane][2] — 2-way banks, b64 ops
  __shared__ float Lmb[2][32];

  const float SCL = 0.18033688f;   // (1/8) * log2(e)
  const float MOFF = 16.0f;

  int phys = blockIdx.x;
  int xcd = phys & 7;
  int cuL = (phys >> 3) & 31;
  int slot = phys >> 8;                 // 0..3
  int bh = xcd * 4 + slot;
  int qt = (slot & 1) ? (31 - cuL) : cuL;

  int tid = threadIdx.x, lane = tid & 63, w = tid >> 6;
  int sub = w & 1, par = w >> 1;
  int l31 = lane & 31, h = lane >> 5;
  const size_t hoff = (size_t)bh * TSEQ * 64;

  int qw = qt * 64 + sub * 32;      // wave's q base
  int qg = qw + l31;                // lane's q column

  // Q B-operand fragments: qf[s] = Q[qg][s*16 + h*8 .. +7]
  bf16x8 qf[4];
  {
    const u16* qp = Qb + hoff + (size_t)qg * 64 + h * 8;
#pragma unroll
    for (int s = 0; s < 4; s++) qf[s] = *(const bf16x8*)(qp + s * 16);
  }

  f32x16 acc[2];
  acc[0] = zero16(); acc[1] = zero16();
  float l_i = 0.f;

  // staging: thread covers K row r cols [cb,cb+16) and V^T row r cols [cb,cb+16)
  int r = tid >> 2, cb = (tid & 3) * 16;
  bf16x8 kr0, kr1, vr0, vr1;
  {
    const u16* kg = Kb + hoff + (size_t)r * 64 + cb;
    const u16* vg = Vtb + hoff + (size_t)r * TSEQ + cb;
    kr0 = *(const bf16x8*)kg;       kr1 = *(const bf16x8*)(kg + 8);
    vr0 = *(const bf16x8*)vg;       vr1 = *(const bf16x8*)(vg + 8);
  }

  for (int kt = 0; kt <= qt; kt++) {
    __syncthreads();                       // prev iter's readers done
    *(bf16x8*)&Ks[r][cb]     = kr0;
    *(bf16x8*)&Ks[r][cb + 8] = kr1;
    *(bf16x8*)&Vt[r][cb]     = vr0;
    *(bf16x8*)&Vt[r][cb + 8] = vr1;
    __syncthreads();                       // tile visible
    if (kt < qt) {                         // prefetch next tile; overlaps compute
      const u16* kg = Kb + hoff + (size_t)((kt + 1) * 64 + r) * 64 + cb;
      const u16* vg = Vtb + hoff + (size_t)r * TSEQ + (kt + 1) * 64 + cb;
      kr0 = *(const bf16x8*)kg;     kr1 = *(const bf16x8*)(kg + 8);
      vr0 = *(const bf16x8*)vg;     vr1 = *(const bf16x8*)(vg + 8);
    }

    int kbt = kt * 64 + par * 32;          // wave's 32-key chunk base
    if (kbt <= qw + 31) {                  // skip fully-masked quadrant (wave-uniform)
      // S^T quadrant = K Q^T : col = q (l31), rows = 32 keys of this chunk
      f32x16 sacc = zero16();
      __builtin_amdgcn_s_setprio(1);
#pragma unroll
      for (int s = 0; s < 4; s++) {
        bf16x8 kf = *(const bf16x8*)&Ks[par * 32 + l31][s * 16 + h * 8];
        sacc = __builtin_amdgcn_mfma_f32_32x32x16_bf16(kf, qf[s], sacc, 0, 0, 0);
      }
      __builtin_amdgcn_s_setprio(0);

      if (kbt + 31 > qw) {                 // diagonal band: apply causal mask
#pragma unroll
        for (int rr = 0; rr < 16; rr++) {
          int key = kbt + (rr & 3) + 8 * (rr >> 2) + 4 * h;
          if (key > qg) sacc[rr] = -1e30f;
        }
      }

#pragma unroll
      for (int rr = 0; rr < 16; rr++) {
        float p = exp2f(__builtin_fmaf(sacc[rr], SCL, -MOFF));
        sacc[rr] = p;
        l_i += p;
      }

      // per 16-key chunk: C->B transform = 4 cvt_pk + 2 permlane32_swap (T12)
#pragma unroll
      for (int s2 = 0; s2 < 2; s2++) {
        u32 u0, u1, u2, u3;
        asm("v_cvt_pk_bf16_f32 %0, %1, %2" : "=v"(u0) : "v"(sacc[8 * s2 + 0]), "v"(sacc[8 * s2 + 1]));
        asm("v_cvt_pk_bf16_f32 %0, %1, %2" : "=v"(u1) : "v"(sacc[8 * s2 + 2]), "v"(sacc[8 * s2 + 3]));
        asm("v_cvt_pk_bf16_f32 %0, %1, %2" : "=v"(u2) : "v"(sacc[8 * s2 + 4]), "v"(sacc[8 * s2 + 5]));
        asm("v_cvt_pk_bf16_f32 %0, %1, %2" : "=v"(u3) : "v"(sacc[8 * s2 + 6]), "v"(sacc[8 * s2 + 7]));
        u32x2 r02 = __builtin_amdgcn_permlane32_swap(u0, u2, false, false);
        u32x2 r13 = __builtin_amdgcn_permlane32_swap(u1, u3, false, false);
        union { u32 d[4]; bf16x8 v; } pf;
        pf.d[0] = r02[0];
        pf.d[1] = r13[0];
        pf.d[2] = r02[1];
        pf.d[3] = r13[1];
        __builtin_amdgcn_s_setprio(1);
#pragma unroll
        for (int dt = 0; dt < 2; dt++) {
          bf16x8 vf = *(const bf16x8*)&Vt[dt * 32 + l31][par * 32 + s2 * 16 + h * 8];
          acc[dt] = __builtin_amdgcn_mfma_f32_32x32x16_bf16(vf, pf.v, acc[dt], 0, 0, 0);
        }
        __builtin_amdgcn_s_setprio(0);
      }
    }
  }

  l_i += __shfl_xor(l_i, 32);              // combine h halves within wave

  __syncthreads();                          // loop LDS traffic done
  if (par == 1) {                           // export partials
#pragma unroll
    for (int dt = 0; dt < 2; dt++)
#pragma unroll
      for (int pr = 0; pr < 8; pr++) {
        Cmb[sub][dt * 8 + pr][lane][0] = acc[dt][2 * pr];
        Cmb[sub][dt * 8 + pr][lane][1] = acc[dt][2 * pr + 1];
      }
    if (h == 0) Lmb[sub][l31] = l_i;
  }
  __syncthreads();
  if (par == 0) {                           // combine + write O
#pragma unroll
    for (int dt = 0; dt < 2; dt++)
#pragma unroll
      for (int pr = 0; pr < 8; pr++) {
        acc[dt][2 * pr]     += Cmb[sub][dt * 8 + pr][lane][0];
        acc[dt][2 * pr + 1] += Cmb[sub][dt * 8 + pr][lane][1];
      }
    float lt = l_i + Lmb[sub][l31];
    float inv = 1.0f / lt;

    int b = bh >> 4, head = bh & 15;
    size_t rowbase = ((size_t)b * TSEQ + qg) * 1024 + head * 64;
#pragma unroll
    for (int dt = 0; dt < 2; dt++)
#pragma unroll
      for (int G = 0; G < 4; G++) {
        union { u32 u[2]; uint2 u2; } o;
        o.u[0] = pack_rn(acc[dt][4 * G + 0] * inv, acc[dt][4 * G + 1] * inv);
        o.u[1] = pack_rn(acc[dt][4 * G + 2] * inv, acc[dt][4 * G + 3] * inv);
        *(uint2*)&O[rowbase + dt * 32 + G * 8 + 4 * h] = o.u2;
      }
  }
}

// ---------------- launch ----------------

extern "C" void kernel_launch(void* const* d_in, const int* in_sizes, int n_in,
                              void* d_out, int out_size, void* d_ws, size_t ws_size,
                              hipStream_t stream) {
  (void)in_sizes; (void)n_in; (void)out_size; (void)ws_size;
  const float* x     = (const float*)d_in[0];
  const float* w_qkv = (const float*)d_in[1];
  const float* b_qkv = (const float*)d_in[2];
  const float* w_out = (const float*)d_in[3];
  const float* b_out = (const float*)d_in[4];
  float* out = (float*)d_out;

  char* p = (char*)d_ws;
  u16* x_bf  = (u16*)p; p += (size_t)TOK * EMB * 2;       // 8 MiB
  u16* wqkvT = (u16*)p; p += (size_t)NQKV * EMB * 2;      // 6 MiB
  u16* woutT = (u16*)p; p += (size_t)EMB * EMB * 2;       // 2 MiB
  u16* Qb    = (u16*)p; p += (size_t)32 * TSEQ * 64 * 2;  // 8 MiB  [bh][t][d]
  u16* Kb    = (u16*)p; p += (size_t)32 * TSEQ * 64 * 2;  //        [bh][t][d]
  u16* Vtb   = (u16*)p; p += (size_t)32 * TSEQ * 64 * 2;  //        [bh][d][t] (direct from gemm0)
  u16* attn_o = (u16*)p;                                  // 8 MiB

  prep_kernel<<<dim3(4096 + 768 + 256), 256, 0, stream>>>(x, x_bf, w_qkv, wqkvT, w_out, woutT);
  // gemm0: grid 768 = 8 XCDs x (12 cols x 8 rows); per-XCD set ~5 MB (R10-proven)
  gemm_bt<0, 128, 12, 8><<<dim3(768), 256, 0, stream>>>(x_bf, wqkvT, b_qkv,
                                                        Qb, Kb, Vtb, nullptr, EMB, NQKV);
  attn_kernel<<<dim3(1024), 256, 0, stream>>>(Qb, Kb, Vtb, attn_o);
  // gemm1: plain 2D grid (remap null here, R10/R11 A/B)
  gemm_bt<1, 64, 0, 0><<<dim3(EMB / 64, TOK / 128), 256, 0, stream>>>(attn_o, woutT, b_out,
                                                                      nullptr, nullptr, nullptr, out, EMB, EMB);
}

// Round 14
// 180.918 us; speedup vs baseline: 1.0184x; 1.0069x over previous
//
#include <hip/hip_runtime.h>

typedef unsigned short u16;
typedef unsigned int u32;
typedef __attribute__((ext_vector_type(2))) unsigned int u32x2;
typedef __attribute__((ext_vector_type(8))) short bf16x8;
typedef __attribute__((ext_vector_type(4))) float f32x4;
typedef __attribute__((ext_vector_type(16))) float f32x16;

#define TOK   4096   // B*T
#define EMB   1024
#define NQKV  3072
#define TSEQ  2048
#define NH    16

__device__ __forceinline__ u16 f2b(float f) {
  union { float f; unsigned u; } v; v.f = f;
  unsigned r = v.u + 0x7FFFu + ((v.u >> 16) & 1u);
  return (u16)(r >> 16);
}

// half-up scalar bf16 (bit-identical to pack_rn's per-half rounding)
__device__ __forceinline__ u16 f2b_hu(float f) {
  return (u16)((__float_as_uint(f) + 0x8000u) >> 16);
}

// pack bf16(a) low16, bf16(b) high16 (round half-up)
__device__ __forceinline__ u32 pack_rn(float a, float b) {
  u32 ua = __float_as_uint(a) + 0x8000u;
  u32 ub = __float_as_uint(b) + 0x8000u;
  return __builtin_amdgcn_perm(ub, ua, 0x07060302u);
}

__device__ __forceinline__ f32x16 zero16() {
  f32x16 z;
#pragma unroll
  for (int i = 0; i < 16; i++) z[i] = 0.f;
  return z;
}

// async global->LDS, 16B per lane; LDS dest is wave-uniform base + lane*16
__device__ __forceinline__ void gload16(const void* g, void* l) {
  __builtin_amdgcn_global_load_lds((const __attribute__((address_space(1))) void*)g,
                                   (__attribute__((address_space(3))) void*)l, 16, 0, 0);
}

// ---------------- fused prep: x->bf16, w_qkv^T, w_out^T ----------------

__global__ __launch_bounds__(256) void prep_kernel(const float* __restrict__ x,
                                                   u16* __restrict__ x_bf,
                                                   const float* __restrict__ w_qkv,
                                                   u16* __restrict__ wqkvT,
                                                   const float* __restrict__ w_out,
                                                   u16* __restrict__ woutT) {
  __shared__ u16 sm[64][65];
  int bid = blockIdx.x, tid = threadIdx.x;
  if (bid < 4096) {                       // cvt: 1M float4 elements
    int i = bid * 256 + tid;
    float4 v = ((const float4*)x)[i];
    union { u16 us[4]; uint2 u2; } o;
    o.us[0] = f2b(v.x); o.us[1] = f2b(v.y); o.us[2] = f2b(v.z); o.us[3] = f2b(v.w);
    ((uint2*)x_bf)[i] = o.u2;
    return;
  }
  const float* src; u16* dst; int R, C, bx, by;
  if (bid < 4096 + 768) {                 // w_qkv: [1024][3072] -> [3072][1024]
    int t = bid - 4096; bx = t % 48; by = t / 48;
    src = w_qkv; dst = wqkvT; R = EMB; C = NQKV;
  } else {                                // w_out: [1024][1024] -> [1024][1024]
    int t = bid - 4096 - 768; bx = t & 15; by = t >> 4;
    src = w_out; dst = woutT; R = EMB; C = EMB;
  }
  int c0 = bx * 64, r0 = by * 64;
#pragma unroll
  for (int i = 0; i < 16; i++) {
    int idx = tid + i * 256;
    int r = idx >> 6, c = idx & 63;
    sm[r][c] = f2b(src[(size_t)(r0 + r) * C + c0 + c]);
  }
  __syncthreads();
  // vectorized writeback: thread -> (cc, 16 consecutive rr) = 2x uint4 stores
  int cc2 = tid >> 2, rr0 = (tid & 3) * 16;
  union { u16 us[16]; uint4 v4[2]; } o;
#pragma unroll
  for (int j = 0; j < 16; j++) o.us[j] = sm[rr0 + j][cc2];
  *(uint4*)&dst[(size_t)(c0 + cc2) * R + r0 + rr0]     = o.v4[0];
  *(uint4*)&dst[(size_t)(c0 + cc2) * R + r0 + rr0 + 8] = o.v4[1];
}

// ---------------- gemm0 (QKV): SESSION-BEST dbuf form + T1 remap ----------------
// Counter-proven: gload_lds w16 + both-sides XOR swizzle (conflicts 0), dbuf
// 2-phase, one __syncthreads/K-step; XCD-chunked remap (FETCH 40->33.9MB,
// 48.4->46.3us). 768 blocks = 3/CU.
// MODE 0 epilogue: Q/K uint2 bf16 [bh][t][d]; V TRANSPOSED [bh][d][t].

template <int MODE, int TN, int CW, int CH>
__global__ __launch_bounds__(256) void gemm_bt(const u16* __restrict__ A,
                                               const u16* __restrict__ Bt,
                                               const float* __restrict__ bias,
                                               u16* __restrict__ qb, u16* __restrict__ kb,
                                               u16* __restrict__ vb, float* __restrict__ outp,
                                               int K, int N) {
  constexpr int CT = TN / 32;            // B col-tiles per wave
  constexpr int RB = TN / 32;            // B staging rounds per wave (8 rows each)
  __shared__ u16 As[2][128][64];
  __shared__ u16 Bs[2][TN][64];
  int tid = threadIdx.x;
  int bx, by;
  if constexpr (CW > 0) {                // T1 chunked remap (bijective)
    int bid = blockIdx.x;
    int xcd = bid & 7, idx = bid >> 3;
    bx = (xcd & 1) * CW + idx % CW;
    by = (xcd >> 1) * CH + idx / CW;
  } else {
    bx = blockIdx.x; by = blockIdx.y;
  }
  int m0 = by * 128, n0 = bx * TN;
  int lane = tid & 63, wid = tid >> 6;
  int wm = (wid >> 1) * 64;
  int wn = (wid & 1) * (TN / 2);
  int l15 = lane & 15, quad = lane >> 4;
  int srow = lane >> 3;
  int scol = (((lane & 7) ^ srow) * 8);

  f32x4 acc[4][CT];
#pragma unroll
  for (int i = 0; i < 4; i++)
#pragma unroll
    for (int j = 0; j < CT; j++) acc[i][j] = (f32x4){0.f, 0.f, 0.f, 0.f};

  const u16* Ag = A + (size_t)(m0 + wid * 32 + srow) * K + scol;
  const u16* Bg = Bt + (size_t)(n0 + wid * (TN / 4) + srow) * K + scol;

  // prologue: stage tile 0 into buf 0
#pragma unroll
  for (int i = 0; i < 4; i++)
    gload16(Ag + (size_t)(i * 8) * K, &As[0][wid * 32 + i * 8][0]);
#pragma unroll
  for (int i = 0; i < RB; i++)
    gload16(Bg + (size_t)(i * 8) * K, &Bs[0][wid * (TN / 4) + i * 8][0]);
  __syncthreads();

  int cur = 0;
  for (int k0 = 0; k0 < K; k0 += 64) {
    if (k0 + 64 < K) {                   // issue next-tile loads; fly under MFMA
      int kn = k0 + 64;
#pragma unroll
      for (int i = 0; i < 4; i++)
        gload16(Ag + (size_t)(i * 8) * K + kn, &As[cur ^ 1][wid * 32 + i * 8][0]);
#pragma unroll
      for (int i = 0; i < RB; i++)
        gload16(Bg + (size_t)(i * 8) * K + kn, &Bs[cur ^ 1][wid * (TN / 4) + i * 8][0]);
    }

#pragma unroll
    for (int ks = 0; ks < 2; ks++) {
      bf16x8 af[4], bfr[CT];
#pragma unroll
      for (int rt = 0; rt < 4; rt++)
        af[rt] = *(const bf16x8*)&As[cur][wm + rt * 16 + l15][((ks * 4 + quad) ^ (l15 & 7)) * 8];
#pragma unroll
      for (int ct = 0; ct < CT; ct++)
        bfr[ct] = *(const bf16x8*)&Bs[cur][wn + ct * 16 + l15][((ks * 4 + quad) ^ (l15 & 7)) * 8];
#pragma unroll
      for (int rt = 0; rt < 4; rt++)
#pragma unroll
        for (int ct = 0; ct < CT; ct++)
          acc[rt][ct] = __builtin_amdgcn_mfma_f32_16x16x32_bf16(bfr[ct], af[rt], acc[rt][ct], 0, 0, 0);
    }
    __syncthreads();                     // vmcnt(0)+lgkmcnt(0)+barrier: next tile
    cur ^= 1;                            // landed, all readers of cur done
  }

#pragma unroll
  for (int rt = 0; rt < 4; rt++) {
#pragma unroll
    for (int ct = 0; ct < CT; ct++) {
      int m = m0 + wm + rt * 16 + l15;
      int nb = n0 + wn + ct * 16 + quad * 4;
      float4 b4 = *(const float4*)&bias[nb];
      float v0 = acc[rt][ct][0] + b4.x, v1 = acc[rt][ct][1] + b4.y;
      float v2 = acc[rt][ct][2] + b4.z, v3 = acc[rt][ct][3] + b4.w;
      if (MODE == 0) {
        int sel = nb >> 10;              // block-uniform (128-col blocks)
        int c = nb & 1023;
        int h = c >> 6, d0 = c & 63;
        int b = m >> 11, t = m & 2047;
        if (sel == 2) {
          // V transposed: Vt[bh][d][t]
          size_t vbase = ((((size_t)b * NH + h) * 64 + d0) * TSEQ) + t;
          vb[vbase]            = f2b_hu(v0);
          vb[vbase + TSEQ]     = f2b_hu(v1);
          vb[vbase + 2 * TSEQ] = f2b_hu(v2);
          vb[vbase + 3 * TSEQ] = f2b_hu(v3);
        } else {
          u16* dst = sel ? kb : qb;
          union { u32 u[2]; uint2 u2; } o;
          o.u[0] = pack_rn(v0, v1);
          o.u[1] = pack_rn(v2, v3);
          *(uint2*)&dst[((((size_t)b * NH + h) * TSEQ + t) << 6) + d0] = o.u2;
        }
      } else {
        float4 o = {v0, v1, v2, v3};
        *(float4*)&outp[(size_t)m * N + nb] = o;
      }
    }
  }
}

// ---------------- gemm1 (out-proj): 3-buffer COUNTED-vmcnt ring ----------------
// The deconfounded counted-wait test (gemm1 measured ~46us for 8.6 GFLOP = 190TF,
// worst-efficiency dispatch). Unlike R6's failed graft: barrier count is
// IDENTICAL to the champion (one per 64-wide K-step) and occupancy is UNCHANGED
// (grid 512 = 2 blocks/CU is grid-limited; LDS 48->72KB still fits 2/CU).
// Depth-2 prefetch: tile k's loads get a full compute step + barrier of cover;
// per-step wait is vmcnt(6) (k+1's loads stay in flight), never 0 mid-loop (T4).
// Hazards: per-wave FIFO vmcnt -> vmcnt(6) proves tile k landed; s_barrier
// collectivizes; buf[(k+2)%3] = buf[(k-1)%3] whose ds_reads completed before
// their MFMAs, which precede this barrier (same contract R6 ran correctly under).

__global__ __launch_bounds__(256) void gemm_out(const u16* __restrict__ A,
                                                const u16* __restrict__ Bt,
                                                const float* __restrict__ bias,
                                                float* __restrict__ outp) {
  constexpr int K = EMB, N = EMB, NSTEP = K / 64;   // 16
  __shared__ u16 As[3][128][64];         // 48 KB
  __shared__ u16 Bs[3][64][64];          // 24 KB  (72 KB total -> still 2 blk/CU)
  int tid = threadIdx.x;
  int n0 = blockIdx.x * 64, m0 = blockIdx.y * 128;
  int lane = tid & 63, wid = tid >> 6;
  int wm = (wid >> 1) * 64;
  int wn = (wid & 1) * 32;
  int l15 = lane & 15, quad = lane >> 4;
  int srow = lane >> 3;
  int scol = (((lane & 7) ^ srow) * 8);

  f32x4 acc[4][2];
#pragma unroll
  for (int i = 0; i < 4; i++)
#pragma unroll
    for (int j = 0; j < 2; j++) acc[i][j] = (f32x4){0.f, 0.f, 0.f, 0.f};

  const u16* Ag = A + (size_t)(m0 + wid * 32 + srow) * K + scol;
  const u16* Bg = Bt + (size_t)(n0 + wid * 16 + srow) * K + scol;

  auto stage = [&](int t) {
    int b = t % 3;
#pragma unroll
    for (int i = 0; i < 4; i++)
      gload16(Ag + (size_t)(i * 8) * K + t * 64, &As[b][wid * 32 + i * 8][0]);
#pragma unroll
    for (int i = 0; i < 2; i++)
      gload16(Bg + (size_t)(i * 8) * K + t * 64, &Bs[b][wid * 16 + i * 8][0]);
  };

  auto compute = [&](int t) {
    int b = t % 3;
#pragma unroll
    for (int ks = 0; ks < 2; ks++) {
      bf16x8 af[4], bfr[2];
#pragma unroll
      for (int rt = 0; rt < 4; rt++)
        af[rt] = *(const bf16x8*)&As[b][wm + rt * 16 + l15][((ks * 4 + quad) ^ (l15 & 7)) * 8];
#pragma unroll
      for (int ct = 0; ct < 2; ct++)
        bfr[ct] = *(const bf16x8*)&Bs[b][wn + ct * 16 + l15][((ks * 4 + quad) ^ (l15 & 7)) * 8];
#pragma unroll
      for (int rt = 0; rt < 4; rt++)
#pragma unroll
        for (int ct = 0; ct < 2; ct++)
          acc[rt][ct] = __builtin_amdgcn_mfma_f32_16x16x32_bf16(bfr[ct], af[rt], acc[rt][ct], 0, 0, 0);
    }
  };

  // prologue: tiles 0 and 1 in flight (6 loads each)
  stage(0);
  stage(1);

  for (int k = 0; k < NSTEP; ++k) {
    if (k < NSTEP - 1) asm volatile("s_waitcnt vmcnt(6)" ::: "memory");  // k done, k+1 in flight
    else               asm volatile("s_waitcnt vmcnt(0)" ::: "memory");  // final drain
    __builtin_amdgcn_s_barrier();        // all waves' tile-k loads landed
    if (k + 2 < NSTEP) stage(k + 2);     // overwrites buf[(k-1)%3]: readers done pre-barrier
    compute(k);
  }

#pragma unroll
  for (int rt = 0; rt < 4; rt++) {
#pragma unroll
    for (int ct = 0; ct < 2; ct++) {
      int m = m0 + wm + rt * 16 + l15;
      int nb = n0 + wn + ct * 16 + quad * 4;
      float4 b4 = *(const float4*)&bias[nb];
      float4 o = {acc[rt][ct][0] + b4.x, acc[rt][ct][1] + b4.y,
                  acc[rt][ct][2] + b4.z, acc[rt][ct][3] + b4.w};
      *(float4*)&outp[(size_t)m * N + nb] = o;
    }
  }
}

// ---------------- flash attention: 32x32 MFMA, 4 waves = 2 q-subtiles x 2 key-halves --
// SESSION-BEST STRUCTURE (R8): grid 1024, 4 blocks/CU, 16 waves/CU; XCD-chunked
// bh (T1); associative fixed-M softmax, par wave-split over keys; T12
// cvt_pk+permlane P transform; T5 setprio around MFMA clusters.

__global__ __launch_bounds__(256, 4) void attn_kernel(const u16* __restrict__ Qb,
                                                      const u16* __restrict__ Kb,
                                                      const u16* __restrict__ Vtb,
                                                      u16* __restrict__ O) {
  __shared__ u16 Ks[64][68];
  __shared__ u16 Vt[64][68];
  __shared__ float Cmb[2][16][64][2];   // [sub][pair][lane][2] — 2-way banks, b64 ops
  __shared__ float Lmb[2][32];

  const float SCL = 0.18033688f;   // (1/8) * log2(e)
  const float MOFF = 16.0f;

  int phys = blockIdx.x;
  int xcd = phys & 7;
  int cuL = (phys >> 3) & 31;
  int slot = phys >> 8;                 // 0..3
  int bh = xcd * 4 + slot;
  int qt = (slot & 1) ? (31 - cuL) : cuL;

  int tid = threadIdx.x, lane = tid & 63, w = tid >> 6;
  int sub = w & 1, par = w >> 1;
  int l31 = lane & 31, h = lane >> 5;
  const size_t hoff = (size_t)bh * TSEQ * 64;

  int qw = qt * 64 + sub * 32;      // wave's q base
  int qg = qw + l31;                // lane's q column

  // Q B-operand fragments: qf[s] = Q[qg][s*16 + h*8 .. +7]
  bf16x8 qf[4];
  {
    const u16* qp = Qb + hoff + (size_t)qg * 64 + h * 8;
#pragma unroll
    for (int s = 0; s < 4; s++) qf[s] = *(const bf16x8*)(qp + s * 16);
  }

  f32x16 acc[2];
  acc[0] = zero16(); acc[1] = zero16();
  float l_i = 0.f;

  // staging: thread covers K row r cols [cb,cb+16) and V^T row r cols [cb,cb+16)
  int r = tid >> 2, cb = (tid & 3) * 16;
  bf16x8 kr0, kr1, vr0, vr1;
  {
    const u16* kg = Kb + hoff + (size_t)r * 64 + cb;
    const u16* vg = Vtb + hoff + (size_t)r * TSEQ + cb;
    kr0 = *(const bf16x8*)kg;       kr1 = *(const bf16x8*)(kg + 8);
    vr0 = *(const bf16x8*)vg;       vr1 = *(const bf16x8*)(vg + 8);
  }

  for (int kt = 0; kt <= qt; kt++) {
    __syncthreads();                       // prev iter's readers done
    *(bf16x8*)&Ks[r][cb]     = kr0;
    *(bf16x8*)&Ks[r][cb + 8] = kr1;
    *(bf16x8*)&Vt[r][cb]     = vr0;
    *(bf16x8*)&Vt[r][cb + 8] = vr1;
    __syncthreads();                       // tile visible
    if (kt < qt) {                         // prefetch next tile; overlaps compute
      const u16* kg = Kb + hoff + (size_t)((kt + 1) * 64 + r) * 64 + cb;
      const u16* vg = Vtb + hoff + (size_t)r * TSEQ + (kt + 1) * 64 + cb;
      kr0 = *(const bf16x8*)kg;     kr1 = *(const bf16x8*)(kg + 8);
      vr0 = *(const bf16x8*)vg;     vr1 = *(const bf16x8*)(vg + 8);
    }

    int kbt = kt * 64 + par * 32;          // wave's 32-key chunk base
    if (kbt <= qw + 31) {                  // skip fully-masked quadrant (wave-uniform)
      // S^T quadrant = K Q^T : col = q (l31), rows = 32 keys of this chunk
      f32x16 sacc = zero16();
      __builtin_amdgcn_s_setprio(1);
#pragma unroll
      for (int s = 0; s < 4; s++) {
        bf16x8 kf = *(const bf16x8*)&Ks[par * 32 + l31][s * 16 + h * 8];
        sacc = __builtin_amdgcn_mfma_f32_32x32x16_bf16(kf, qf[s], sacc, 0, 0, 0);
      }
      __builtin_amdgcn_s_setprio(0);

      if (kbt + 31 > qw) {                 // diagonal band: apply causal mask
#pragma unroll
        for (int rr = 0; rr < 16; rr++) {
          int key = kbt + (rr & 3) + 8 * (rr >> 2) + 4 * h;
          if (key > qg) sacc[rr] = -1e30f;
        }
      }

#pragma unroll
      for (int rr = 0; rr < 16; rr++) {
        float p = exp2f(__builtin_fmaf(sacc[rr], SCL, -MOFF));
        sacc[rr] = p;
        l_i += p;
      }

      // per 16-key chunk: C->B transform = 4 cvt_pk + 2 permlane32_swap (T12)
#pragma unroll
      for (int s2 = 0; s2 < 2; s2++) {
        u32 u0, u1, u2, u3;
        asm("v_cvt_pk_bf16_f32 %0, %1, %2" : "=v"(u0) : "v"(sacc[8 * s2 + 0]), "v"(sacc[8 * s2 + 1]));
        asm("v_cvt_pk_bf16_f32 %0, %1, %2" : "=v"(u1) : "v"(sacc[8 * s2 + 2]), "v"(sacc[8 * s2 + 3]));
        asm("v_cvt_pk_bf16_f32 %0, %1, %2" : "=v"(u2) : "v"(sacc[8 * s2 + 4]), "v"(sacc[8 * s2 + 5]));
        asm("v_cvt_pk_bf16_f32 %0, %1, %2" : "=v"(u3) : "v"(sacc[8 * s2 + 6]), "v"(sacc[8 * s2 + 7]));
        u32x2 r02 = __builtin_amdgcn_permlane32_swap(u0, u2, false, false);
        u32x2 r13 = __builtin_amdgcn_permlane32_swap(u1, u3, false, false);
        union { u32 d[4]; bf16x8 v; } pf;
        pf.d[0] = r02[0];
        pf.d[1] = r13[0];
        pf.d[2] = r02[1];
        pf.d[3] = r13[1];
        __builtin_amdgcn_s_setprio(1);
#pragma unroll
        for (int dt = 0; dt < 2; dt++) {
          bf16x8 vf = *(const bf16x8*)&Vt[dt * 32 + l31][par * 32 + s2 * 16 + h * 8];
          acc[dt] = __builtin_amdgcn_mfma_f32_32x32x16_bf16(vf, pf.v, acc[dt], 0, 0, 0);
        }
        __builtin_amdgcn_s_setprio(0);
      }
    }
  }

  l_i += __shfl_xor(l_i, 32);              // combine h halves within wave

  __syncthreads();                          // loop LDS traffic done
  if (par == 1) {                           // export partials
#pragma unroll
    for (int dt = 0; dt < 2; dt++)
#pragma unroll
      for (int pr = 0; pr < 8; pr++) {
        Cmb[sub][dt * 8 + pr][lane][0] = acc[dt][2 * pr];
        Cmb[sub][dt * 8 + pr][lane][1] = acc[dt][2 * pr + 1];
      }
    if (h == 0) Lmb[sub][l31] = l_i;
  }
  __syncthreads();
  if (par == 0) {                           // combine + write O
#pragma unroll
    for (int dt = 0; dt < 2; dt++)
#pragma unroll
      for (int pr = 0; pr < 8; pr++) {
        acc[dt][2 * pr]     += Cmb[sub][dt * 8 + pr][lane][0];
        acc[dt][2 * pr + 1] += Cmb[sub][dt * 8 + pr][lane][1];
      }
    float lt = l_i + Lmb[sub][l31];
    float inv = 1.0f / lt;

    int b = bh >> 4, head = bh & 15;
    size_t rowbase = ((size_t)b * TSEQ + qg) * 1024 + head * 64;
#pragma unroll
    for (int dt = 0; dt < 2; dt++)
#pragma unroll
      for (int G = 0; G < 4; G++) {
        union { u32 u[2]; uint2 u2; } o;
        o.u[0] = pack_rn(acc[dt][4 * G + 0] * inv, acc[dt][4 * G + 1] * inv);
        o.u[1] = pack_rn(acc[dt][4 * G + 2] * inv, acc[dt][4 * G + 3] * inv);
        *(uint2*)&O[rowbase + dt * 32 + G * 8 + 4 * h] = o.u2;
      }
  }
}

// ---------------- launch ----------------

extern "C" void kernel_launch(void* const* d_in, const int* in_sizes, int n_in,
                              void* d_out, int out_size, void* d_ws, size_t ws_size,
                              hipStream_t stream) {
  (void)in_sizes; (void)n_in; (void)out_size; (void)ws_size;
  const float* x     = (const float*)d_in[0];
  const float* w_qkv = (const float*)d_in[1];
  const float* b_qkv = (const float*)d_in[2];
  const float* w_out = (const float*)d_in[3];
  const float* b_out = (const float*)d_in[4];
  float* out = (float*)d_out;

  char* p = (char*)d_ws;
  u16* x_bf  = (u16*)p; p += (size_t)TOK * EMB * 2;       // 8 MiB
  u16* wqkvT = (u16*)p; p += (size_t)NQKV * EMB * 2;      // 6 MiB
  u16* woutT = (u16*)p; p += (size_t)EMB * EMB * 2;       // 2 MiB
  u16* Qb    = (u16*)p; p += (size_t)32 * TSEQ * 64 * 2;  // 8 MiB  [bh][t][d]
  u16* Kb    = (u16*)p; p += (size_t)32 * TSEQ * 64 * 2;  //        [bh][t][d]
  u16* Vtb   = (u16*)p; p += (size_t)32 * TSEQ * 64 * 2;  //        [bh][d][t] (direct from gemm0)
  u16* attn_o = (u16*)p;                                  // 8 MiB

  prep_kernel<<<dim3(4096 + 768 + 256), 256, 0, stream>>>(x, x_bf, w_qkv, wqkvT, w_out, woutT);
  // gemm0: grid 768 = 8 XCDs x (12 cols x 8 rows); per-XCD set ~5 MB (R10-proven)
  gemm_bt<0, 128, 12, 8><<<dim3(768), 256, 0, stream>>>(x_bf, wqkvT, b_qkv,
                                                        Qb, Kb, Vtb, nullptr, EMB, NQKV);
  attn_kernel<<<dim3(1024), 256, 0, stream>>>(Qb, Kb, Vtb, attn_o);
  // gemm1: 3-buffer counted-vmcnt ring (grid 512 = 2/CU, occupancy-neutral)
  gemm_out<<<dim3(EMB / 64, TOK / 128), 256, 0, stream>>>(attn_o, woutT, b_out, out);
}

// Round 15
// 180.861 us; speedup vs baseline: 1.0187x; 1.0003x over previous
//
#include <hip/hip_runtime.h>

typedef unsigned short u16;
typedef unsigned int u32;
typedef __attribute__((ext_vector_type(2))) unsigned int u32x2;
typedef __attribute__((ext_vector_type(8))) short bf16x8;
typedef __attribute__((ext_vector_type(4))) float f32x4;
typedef __attribute__((ext_vector_type(16))) float f32x16;

#define TOK   4096   // B*T
#define EMB   1024
#define NQKV  3072
#define TSEQ  2048
#define NH    16

__device__ __forceinline__ u16 f2b(float f) {
  union { float f; unsigned u; } v; v.f = f;
  unsigned r = v.u + 0x7FFFu + ((v.u >> 16) & 1u);
  return (u16)(r >> 16);
}

// half-up scalar bf16 (bit-identical to pack_rn's per-half rounding)
__device__ __forceinline__ u16 f2b_hu(float f) {
  return (u16)((__float_as_uint(f) + 0x8000u) >> 16);
}

// pack bf16(a) low16, bf16(b) high16 (round half-up)
__device__ __forceinline__ u32 pack_rn(float a, float b) {
  u32 ua = __float_as_uint(a) + 0x8000u;
  u32 ub = __float_as_uint(b) + 0x8000u;
  return __builtin_amdgcn_perm(ub, ua, 0x07060302u);
}

__device__ __forceinline__ f32x16 zero16() {
  f32x16 z;
#pragma unroll
  for (int i = 0; i < 16; i++) z[i] = 0.f;
  return z;
}

// async global->LDS, 16B per lane; LDS dest is wave-uniform base + lane*16
__device__ __forceinline__ void gload16(const void* g, void* l) {
  __builtin_amdgcn_global_load_lds((const __attribute__((address_space(1))) void*)g,
                                   (__attribute__((address_space(3))) void*)l, 16, 0, 0);
}

// ---------------- fused prep: x->bf16, w_qkv^T, w_out^T ----------------
// cvt section: 32B/thread (2x float4 in, 1x uint4 out) -- G13 16B/lane store.

__global__ __launch_bounds__(256) void prep_kernel(const float* __restrict__ x,
                                                   u16* __restrict__ x_bf,
                                                   const float* __restrict__ w_qkv,
                                                   u16* __restrict__ wqkvT,
                                                   const float* __restrict__ w_out,
                                                   u16* __restrict__ woutT) {
  __shared__ u16 sm[64][65];
  int bid = blockIdx.x, tid = threadIdx.x;
  if (bid < 2048) {                       // cvt: thread j covers float4s 2j,2j+1
    int j = bid * 256 + tid;
    float4 v0 = ((const float4*)x)[2 * j];
    float4 v1 = ((const float4*)x)[2 * j + 1];
    union { u16 us[8]; uint4 u4; } o;
    o.us[0] = f2b(v0.x); o.us[1] = f2b(v0.y); o.us[2] = f2b(v0.z); o.us[3] = f2b(v0.w);
    o.us[4] = f2b(v1.x); o.us[5] = f2b(v1.y); o.us[6] = f2b(v1.z); o.us[7] = f2b(v1.w);
    ((uint4*)x_bf)[j] = o.u4;
    return;
  }
  const float* src; u16* dst; int R, C, bx, by;
  if (bid < 2048 + 768) {                 // w_qkv: [1024][3072] -> [3072][1024]
    int t = bid - 2048; bx = t % 48; by = t / 48;
    src = w_qkv; dst = wqkvT; R = EMB; C = NQKV;
  } else {                                // w_out: [1024][1024] -> [1024][1024]
    int t = bid - 2048 - 768; bx = t & 15; by = t >> 4;
    src = w_out; dst = woutT; R = EMB; C = EMB;
  }
  int c0 = bx * 64, r0 = by * 64;
#pragma unroll
  for (int i = 0; i < 16; i++) {
    int idx = tid + i * 256;
    int r = idx >> 6, c = idx & 63;
    sm[r][c] = f2b(src[(size_t)(r0 + r) * C + c0 + c]);
  }
  __syncthreads();
  // vectorized writeback: thread -> (cc, 16 consecutive rr) = 2x uint4 stores
  int cc2 = tid >> 2, rr0 = (tid & 3) * 16;
  union { u16 us[16]; uint4 v4[2]; } o;
#pragma unroll
  for (int j = 0; j < 16; j++) o.us[j] = sm[rr0 + j][cc2];
  *(uint4*)&dst[(size_t)(c0 + cc2) * R + r0 + rr0]     = o.v4[0];
  *(uint4*)&dst[(size_t)(c0 + cc2) * R + r0 + rr0 + 8] = o.v4[1];
}

// ---------------- gemm0 (QKV): SESSION-BEST dbuf form + T1 remap ----------------
// Counter-proven: gload_lds w16 + both-sides XOR swizzle (conflicts 0), dbuf
// 2-phase, one __syncthreads/K-step; XCD-chunked remap (FETCH 40->33.9MB,
// 48.4->46.3us). 768 blocks = 3/CU.
// MODE 0 epilogue: Q/K uint2 bf16 [bh][t][d]; V TRANSPOSED [bh][d][t].

template <int MODE, int TN, int CW, int CH>
__global__ __launch_bounds__(256) void gemm_bt(const u16* __restrict__ A,
                                               const u16* __restrict__ Bt,
                                               const float* __restrict__ bias,
                                               u16* __restrict__ qb, u16* __restrict__ kb,
                                               u16* __restrict__ vb, float* __restrict__ outp,
                                               int K, int N) {
  constexpr int CT = TN / 32;            // B col-tiles per wave
  constexpr int RB = TN / 32;            // B staging rounds per wave (8 rows each)
  __shared__ u16 As[2][128][64];
  __shared__ u16 Bs[2][TN][64];
  int tid = threadIdx.x;
  int bx, by;
  if constexpr (CW > 0) {                // T1 chunked remap (bijective)
    int bid = blockIdx.x;
    int xcd = bid & 7, idx = bid >> 3;
    bx = (xcd & 1) * CW + idx % CW;
    by = (xcd >> 1) * CH + idx / CW;
  } else {
    bx = blockIdx.x; by = blockIdx.y;
  }
  int m0 = by * 128, n0 = bx * TN;
  int lane = tid & 63, wid = tid >> 6;
  int wm = (wid >> 1) * 64;
  int wn = (wid & 1) * (TN / 2);
  int l15 = lane & 15, quad = lane >> 4;
  int srow = lane >> 3;
  int scol = (((lane & 7) ^ srow) * 8);

  f32x4 acc[4][CT];
#pragma unroll
  for (int i = 0; i < 4; i++)
#pragma unroll
    for (int j = 0; j < CT; j++) acc[i][j] = (f32x4){0.f, 0.f, 0.f, 0.f};

  const u16* Ag = A + (size_t)(m0 + wid * 32 + srow) * K + scol;
  const u16* Bg = Bt + (size_t)(n0 + wid * (TN / 4) + srow) * K + scol;

  // prologue: stage tile 0 into buf 0
#pragma unroll
  for (int i = 0; i < 4; i++)
    gload16(Ag + (size_t)(i * 8) * K, &As[0][wid * 32 + i * 8][0]);
#pragma unroll
  for (int i = 0; i < RB; i++)
    gload16(Bg + (size_t)(i * 8) * K, &Bs[0][wid * (TN / 4) + i * 8][0]);
  __syncthreads();

  int cur = 0;
  for (int k0 = 0; k0 < K; k0 += 64) {
    if (k0 + 64 < K) {                   // issue next-tile loads; fly under MFMA
      int kn = k0 + 64;
#pragma unroll
      for (int i = 0; i < 4; i++)
        gload16(Ag + (size_t)(i * 8) * K + kn, &As[cur ^ 1][wid * 32 + i * 8][0]);
#pragma unroll
      for (int i = 0; i < RB; i++)
        gload16(Bg + (size_t)(i * 8) * K + kn, &Bs[cur ^ 1][wid * (TN / 4) + i * 8][0]);
    }

#pragma unroll
    for (int ks = 0; ks < 2; ks++) {
      bf16x8 af[4], bfr[CT];
#pragma unroll
      for (int rt = 0; rt < 4; rt++)
        af[rt] = *(const bf16x8*)&As[cur][wm + rt * 16 + l15][((ks * 4 + quad) ^ (l15 & 7)) * 8];
#pragma unroll
      for (int ct = 0; ct < CT; ct++)
        bfr[ct] = *(const bf16x8*)&Bs[cur][wn + ct * 16 + l15][((ks * 4 + quad) ^ (l15 & 7)) * 8];
#pragma unroll
      for (int rt = 0; rt < 4; rt++)
#pragma unroll
        for (int ct = 0; ct < CT; ct++)
          acc[rt][ct] = __builtin_amdgcn_mfma_f32_16x16x32_bf16(bfr[ct], af[rt], acc[rt][ct], 0, 0, 0);
    }
    __syncthreads();                     // vmcnt(0)+lgkmcnt(0)+barrier: next tile
    cur ^= 1;                            // landed, all readers of cur done
  }

#pragma unroll
  for (int rt = 0; rt < 4; rt++) {
#pragma unroll
    for (int ct = 0; ct < CT; ct++) {
      int m = m0 + wm + rt * 16 + l15;
      int nb = n0 + wn + ct * 16 + quad * 4;
      float4 b4 = *(const float4*)&bias[nb];
      float v0 = acc[rt][ct][0] + b4.x, v1 = acc[rt][ct][1] + b4.y;
      float v2 = acc[rt][ct][2] + b4.z, v3 = acc[rt][ct][3] + b4.w;
      if (MODE == 0) {
        int sel = nb >> 10;              // block-uniform (128-col blocks)
        int c = nb & 1023;
        int h = c >> 6, d0 = c & 63;
        int b = m >> 11, t = m & 2047;
        if (sel == 2) {
          // V transposed: Vt[bh][d][t]
          size_t vbase = ((((size_t)b * NH + h) * 64 + d0) * TSEQ) + t;
          vb[vbase]            = f2b_hu(v0);
          vb[vbase + TSEQ]     = f2b_hu(v1);
          vb[vbase + 2 * TSEQ] = f2b_hu(v2);
          vb[vbase + 3 * TSEQ] = f2b_hu(v3);
        } else {
          u16* dst = sel ? kb : qb;
          union { u32 u[2]; uint2 u2; } o;
          o.u[0] = pack_rn(v0, v1);
          o.u[1] = pack_rn(v2, v3);
          *(uint2*)&dst[((((size_t)b * NH + h) * TSEQ + t) << 6) + d0] = o.u2;
        }
      } else {
        float4 o = {v0, v1, v2, v3};
        *(float4*)&outp[(size_t)m * N + nb] = o;
      }
    }
  }
}

// ---------------- gemm1 (out-proj): 3-buffer COUNTED-vmcnt ring (R14-proven) ----------------
// Occupancy-neutral T4 deployment: barrier count identical to champion (one per
// 64-wide K-step), grid 512 = 2 blk/CU grid-limited, LDS 72KB still 2/CU.
// Depth-2 prefetch, per-step wait vmcnt(6) (k+1's loads stay in flight), never 0
// mid-loop. R14: total 182.2 -> 180.9 with this kernel swapped in.

__global__ __launch_bounds__(256) void gemm_out(const u16* __restrict__ A,
                                                const u16* __restrict__ Bt,
                                                const float* __restrict__ bias,
                                                float* __restrict__ outp) {
  constexpr int K = EMB, N = EMB, NSTEP = K / 64;   // 16
  __shared__ u16 As[3][128][64];         // 48 KB
  __shared__ u16 Bs[3][64][64];          // 24 KB  (72 KB total -> still 2 blk/CU)
  int tid = threadIdx.x;
  int n0 = blockIdx.x * 64, m0 = blockIdx.y * 128;
  int lane = tid & 63, wid = tid >> 6;
  int wm = (wid >> 1) * 64;
  int wn = (wid & 1) * 32;
  int l15 = lane & 15, quad = lane >> 4;
  int srow = lane >> 3;
  int scol = (((lane & 7) ^ srow) * 8);

  f32x4 acc[4][2];
#pragma unroll
  for (int i = 0; i < 4; i++)
#pragma unroll
    for (int j = 0; j < 2; j++) acc[i][j] = (f32x4){0.f, 0.f, 0.f, 0.f};

  const u16* Ag = A + (size_t)(m0 + wid * 32 + srow) * K + scol;
  const u16* Bg = Bt + (size_t)(n0 + wid * 16 + srow) * K + scol;

  auto stage = [&](int t) {
    int b = t % 3;
#pragma unroll
    for (int i = 0; i < 4; i++)
      gload16(Ag + (size_t)(i * 8) * K + t * 64, &As[b][wid * 32 + i * 8][0]);
#pragma unroll
    for (int i = 0; i < 2; i++)
      gload16(Bg + (size_t)(i * 8) * K + t * 64, &Bs[b][wid * 16 + i * 8][0]);
  };

  auto compute = [&](int t) {
    int b = t % 3;
#pragma unroll
    for (int ks = 0; ks < 2; ks++) {
      bf16x8 af[4], bfr[2];
#pragma unroll
      for (int rt = 0; rt < 4; rt++)
        af[rt] = *(const bf16x8*)&As[b][wm + rt * 16 + l15][((ks * 4 + quad) ^ (l15 & 7)) * 8];
#pragma unroll
      for (int ct = 0; ct < 2; ct++)
        bfr[ct] = *(const bf16x8*)&Bs[b][wn + ct * 16 + l15][((ks * 4 + quad) ^ (l15 & 7)) * 8];
#pragma unroll
      for (int rt = 0; rt < 4; rt++)
#pragma unroll
        for (int ct = 0; ct < 2; ct++)
          acc[rt][ct] = __builtin_amdgcn_mfma_f32_16x16x32_bf16(bfr[ct], af[rt], acc[rt][ct], 0, 0, 0);
    }
  };

  // prologue: tiles 0 and 1 in flight (6 loads each)
  stage(0);
  stage(1);

  for (int k = 0; k < NSTEP; ++k) {
    if (k < NSTEP - 1) asm volatile("s_waitcnt vmcnt(6)" ::: "memory");  // k done, k+1 in flight
    else               asm volatile("s_waitcnt vmcnt(0)" ::: "memory");  // final drain
    __builtin_amdgcn_s_barrier();        // all waves' tile-k loads landed
    if (k + 2 < NSTEP) stage(k + 2);     // overwrites buf[(k-1)%3]: readers done pre-barrier
    compute(k);
  }

#pragma unroll
  for (int rt = 0; rt < 4; rt++) {
#pragma unroll
    for (int ct = 0; ct < 2; ct++) {
      int m = m0 + wm + rt * 16 + l15;
      int nb = n0 + wn + ct * 16 + quad * 4;
      float4 b4 = *(const float4*)&bias[nb];
      float4 o = {acc[rt][ct][0] + b4.x, acc[rt][ct][1] + b4.y,
                  acc[rt][ct][2] + b4.z, acc[rt][ct][3] + b4.w};
      *(float4*)&outp[(size_t)m * N + nb] = o;
    }
  }
}

// ---------------- flash attention: 32x32 MFMA, 4 waves = 2 q-subtiles x 2 key-halves --
// SESSION-BEST STRUCTURE (R8): grid 1024, 4 blocks/CU, 16 waves/CU; XCD-chunked
// bh (T1); associative fixed-M softmax, par wave-split over keys; T12
// cvt_pk+permlane P transform; T5 setprio around MFMA clusters.

__global__ __launch_bounds__(256, 4) void attn_kernel(const u16* __restrict__ Qb,
                                                      const u16* __restrict__ Kb,
                                                      const u16* __restrict__ Vtb,
                                                      u16* __restrict__ O) {
  __shared__ u16 Ks[64][68];
  __shared__ u16 Vt[64][68];
  __shared__ float Cmb[2][16][64][2];   // [sub][pair][lane][2] — 2-way banks, b64 ops
  __shared__ float Lmb[2][32];

  const float SCL = 0.18033688f;   // (1/8) * log2(e)
  const float MOFF = 16.0f;

  int phys = blockIdx.x;
  int xcd = phys & 7;
  int cuL = (phys >> 3) & 31;
  int slot = phys >> 8;                 // 0..3
  int bh = xcd * 4 + slot;
  int qt = (slot & 1) ? (31 - cuL) : cuL;

  int tid = threadIdx.x, lane = tid & 63, w = tid >> 6;
  int sub = w & 1, par = w >> 1;
  int l31 = lane & 31, h = lane >> 5;
  const size_t hoff = (size_t)bh * TSEQ * 64;

  int qw = qt * 64 + sub * 32;      // wave's q base
  int qg = qw + l31;                // lane's q column

  // Q B-operand fragments: qf[s] = Q[qg][s*16 + h*8 .. +7]
  bf16x8 qf[4];
  {
    const u16* qp = Qb + hoff + (size_t)qg * 64 + h * 8;
#pragma unroll
    for (int s = 0; s < 4; s++) qf[s] = *(const bf16x8*)(qp + s * 16);
  }

  f32x16 acc[2];
  acc[0] = zero16(); acc[1] = zero16();
  float l_i = 0.f;

  // staging: thread covers K row r cols [cb,cb+16) and V^T row r cols [cb,cb+16)
  int r = tid >> 2, cb = (tid & 3) * 16;
  bf16x8 kr0, kr1, vr0, vr1;
  {
    const u16* kg = Kb + hoff + (size_t)r * 64 + cb;
    const u16* vg = Vtb + hoff + (size_t)r * TSEQ + cb;
    kr0 = *(const bf16x8*)kg;       kr1 = *(const bf16x8*)(kg + 8);
    vr0 = *(const bf16x8*)vg;       vr1 = *(const bf16x8*)(vg + 8);
  }

  for (int kt = 0; kt <= qt; kt++) {
    __syncthreads();                       // prev iter's readers done
    *(bf16x8*)&Ks[r][cb]     = kr0;
    *(bf16x8*)&Ks[r][cb + 8] = kr1;
    *(bf16x8*)&Vt[r][cb]     = vr0;
    *(bf16x8*)&Vt[r][cb + 8] = vr1;
    __syncthreads();                       // tile visible
    if (kt < qt) {                         // prefetch next tile; overlaps compute
      const u16* kg = Kb + hoff + (size_t)((kt + 1) * 64 + r) * 64 + cb;
      const u16* vg = Vtb + hoff + (size_t)r * TSEQ + (kt + 1) * 64 + cb;
      kr0 = *(const bf16x8*)kg;     kr1 = *(const bf16x8*)(kg + 8);
      vr0 = *(const bf16x8*)vg;     vr1 = *(const bf16x8*)(vg + 8);
    }

    int kbt = kt * 64 + par * 32;          // wave's 32-key chunk base
    if (kbt <= qw + 31) {                  // skip fully-masked quadrant (wave-uniform)
      // S^T quadrant = K Q^T : col = q (l31), rows = 32 keys of this chunk
      f32x16 sacc = zero16();
      __builtin_amdgcn_s_setprio(1);
#pragma unroll
      for (int s = 0; s < 4; s++) {
        bf16x8 kf = *(const bf16x8*)&Ks[par * 32 + l31][s * 16 + h * 8];
        sacc = __builtin_amdgcn_mfma_f32_32x32x16_bf16(kf, qf[s], sacc, 0, 0, 0);
      }
      __builtin_amdgcn_s_setprio(0);

      if (kbt + 31 > qw) {                 // diagonal band: apply causal mask
#pragma unroll
        for (int rr = 0; rr < 16; rr++) {
          int key = kbt + (rr & 3) + 8 * (rr >> 2) + 4 * h;
          if (key > qg) sacc[rr] = -1e30f;
        }
      }

#pragma unroll
      for (int rr = 0; rr < 16; rr++) {
        float p = exp2f(__builtin_fmaf(sacc[rr], SCL, -MOFF));
        sacc[rr] = p;
        l_i += p;
      }

      // per 16-key chunk: C->B transform = 4 cvt_pk + 2 permlane32_swap (T12)
#pragma unroll
      for (int s2 = 0; s2 < 2; s2++) {
        u32 u0, u1, u2, u3;
        asm("v_cvt_pk_bf16_f32 %0, %1, %2" : "=v"(u0) : "v"(sacc[8 * s2 + 0]), "v"(sacc[8 * s2 + 1]));
        asm("v_cvt_pk_bf16_f32 %0, %1, %2" : "=v"(u1) : "v"(sacc[8 * s2 + 2]), "v"(sacc[8 * s2 + 3]));
        asm("v_cvt_pk_bf16_f32 %0, %1, %2" : "=v"(u2) : "v"(sacc[8 * s2 + 4]), "v"(sacc[8 * s2 + 5]));
        asm("v_cvt_pk_bf16_f32 %0, %1, %2" : "=v"(u3) : "v"(sacc[8 * s2 + 6]), "v"(sacc[8 * s2 + 7]));
        u32x2 r02 = __builtin_amdgcn_permlane32_swap(u0, u2, false, false);
        u32x2 r13 = __builtin_amdgcn_permlane32_swap(u1, u3, false, false);
        union { u32 d[4]; bf16x8 v; } pf;
        pf.d[0] = r02[0];
        pf.d[1] = r13[0];
        pf.d[2] = r02[1];
        pf.d[3] = r13[1];
        __builtin_amdgcn_s_setprio(1);
#pragma unroll
        for (int dt = 0; dt < 2; dt++) {
          bf16x8 vf = *(const bf16x8*)&Vt[dt * 32 + l31][par * 32 + s2 * 16 + h * 8];
          acc[dt] = __builtin_amdgcn_mfma_f32_32x32x16_bf16(vf, pf.v, acc[dt], 0, 0, 0);
        }
        __builtin_amdgcn_s_setprio(0);
      }
    }
  }

  l_i += __shfl_xor(l_i, 32);              // combine h halves within wave

  __syncthreads();                          // loop LDS traffic done
  if (par == 1) {                           // export partials
#pragma unroll
    for (int dt = 0; dt < 2; dt++)
#pragma unroll
      for (int pr = 0; pr < 8; pr++) {
        Cmb[sub][dt * 8 + pr][lane][0] = acc[dt][2 * pr];
        Cmb[sub][dt * 8 + pr][lane][1] = acc[dt][2 * pr + 1];
      }
    if (h == 0) Lmb[sub][l31] = l_i;
  }
  __syncthreads();
  if (par == 0) {                           // combine + write O
#pragma unroll
    for (int dt = 0; dt < 2; dt++)
#pragma unroll
      for (int pr = 0; pr < 8; pr++) {
        acc[dt][2 * pr]     += Cmb[sub][dt * 8 + pr][lane][0];
        acc[dt][2 * pr + 1] += Cmb[sub][dt * 8 + pr][lane][1];
      }
    float lt = l_i + Lmb[sub][l31];
    float inv = 1.0f / lt;

    int b = bh >> 4, head = bh & 15;
    size_t rowbase = ((size_t)b * TSEQ + qg) * 1024 + head * 64;
#pragma unroll
    for (int dt = 0; dt < 2; dt++)
#pragma unroll
      for (int G = 0; G < 4; G++) {
        union { u32 u[2]; uint2 u2; } o;
        o.u[0] = pack_rn(acc[dt][4 * G + 0] * inv, acc[dt][4 * G + 1] * inv);
        o.u[1] = pack_rn(acc[dt][4 * G + 2] * inv, acc[dt][4 * G + 3] * inv);
        *(uint2*)&O[rowbase + dt * 32 + G * 8 + 4 * h] = o.u2;
      }
  }
}

// ---------------- launch ----------------

extern "C" void kernel_launch(void* const* d_in, const int* in_sizes, int n_in,
                              void* d_out, int out_size, void* d_ws, size_t ws_size,
                              hipStream_t stream) {
  (void)in_sizes; (void)n_in; (void)out_size; (void)ws_size;
  const float* x     = (const float*)d_in[0];
  const float* w_qkv = (const float*)d_in[1];
  const float* b_qkv = (const float*)d_in[2];
  const float* w_out = (const float*)d_in[3];
  const float* b_out = (const float*)d_in[4];
  float* out = (float*)d_out;

  char* p = (char*)d_ws;
  u16* x_bf  = (u16*)p; p += (size_t)TOK * EMB * 2;       // 8 MiB
  u16* wqkvT = (u16*)p; p += (size_t)NQKV * EMB * 2;      // 6 MiB
  u16* woutT = (u16*)p; p += (size_t)EMB * EMB * 2;       // 2 MiB
  u16* Qb    = (u16*)p; p += (size_t)32 * TSEQ * 64 * 2;  // 8 MiB  [bh][t][d]
  u16* Kb    = (u16*)p; p += (size_t)32 * TSEQ * 64 * 2;  //        [bh][t][d]
  u16* Vtb   = (u16*)p; p += (size_t)32 * TSEQ * 64 * 2;  //        [bh][d][t] (direct from gemm0)
  u16* attn_o = (u16*)p;                                  // 8 MiB

  prep_kernel<<<dim3(2048 + 768 + 256), 256, 0, stream>>>(x, x_bf, w_qkv, wqkvT, w_out, woutT);
  // gemm0: grid 768 = 8 XCDs x (12 cols x 8 rows); per-XCD set ~5 MB (R10-proven)
  gemm_bt<0, 128, 12, 8><<<dim3(768), 256, 0, stream>>>(x_bf, wqkvT, b_qkv,
                                                        Qb, Kb, Vtb, nullptr, EMB, NQKV);
  attn_kernel<<<dim3(1024), 256, 0, stream>>>(Qb, Kb, Vtb, attn_o);
  // gemm1: 3-buffer counted-vmcnt ring (R14-proven)
  gemm_out<<<dim3(EMB / 64, TOK / 128), 256, 0, stream>>>(attn_o, woutT, b_out, out);
}